// Round 26
// baseline (134.980 us; speedup 1.0000x reference)
//
#include <hip/hip_runtime.h>
#include <math.h>

// ---------------- dims ----------------
#define SQ 197           // tokens
#define DD 768           // hidden
#define NHH 12
#define DHH 64
#define BB_ 64           // batch
#define MTOK (BB_*SQ)    // 12608
#define MPATCH (BB_*196) // 12544
#define NOUT 1000
#define LNN (SQ*DD)      // 151296 elems per sample
#define SQP 256          // padded seq for vT

typedef unsigned short u16;
typedef __attribute__((ext_vector_type(8))) short bf16x8;
typedef __attribute__((ext_vector_type(4))) float f32x4;

__device__ __forceinline__ u16 f2bf(float x) {      // RNE f32->bf16
    unsigned u = __float_as_uint(x);
    u = (u + 0x7FFF + ((u >> 16) & 1)) >> 16;
    return (u16)u;
}
__device__ __forceinline__ float bf2f(u16 x) {
    return __uint_as_float(((unsigned)x) << 16);
}

// ---------------- fused prologue: pos_emb | cls | transpose(w_map) | wqkv_prep | conv ----------------
__global__ __launch_bounds__(256) void prep_kernel(
        const float* __restrict__ cls_tok, const float* __restrict__ images,
        const float* __restrict__ w_map,
        const float* __restrict__ wq, const float* __restrict__ wk,
        const float* __restrict__ wv,
        float* __restrict__ pos, u16* __restrict__ tokens,
        float* __restrict__ cpart, u16* __restrict__ imb,
        u16* __restrict__ wt, u16* __restrict__ wTg) {
    __shared__ float tbuf[64*65];              // 16.6 KB, aliased per branch
    const int blk = blockIdx.x, tid = threadIdx.x;

    if (blk < 592) {                           // ---- pos_emb ----
        int i = blk * 256 + tid;
        if (i < SQ * DD) {
            int s = i / DD, d = i % DD;
            double e = (double)(d & ~1) / (double)DD;
            double ang = (double)s * pow(10000.0, -e);
            pos[i] = (d & 1) ? (float)cos(ang) : (float)sin(ang);
        }
        return;
    }
    if (blk < 784) {                           // ---- cls + LN1 partials ----
        const int b2 = blk - 592;
        const int i = b2 * 256 + tid;
        const int b = i / DD, d = i % DD;
        float v = cls_tok[d] + ((d & 1) ? 1.0f : 0.0f);
        tokens[(size_t)b * SQ * DD + d] = f2bf(v);
        float ps = v, ps2 = v * v;
        const int w = tid >> 6, l = tid & 63;
#pragma unroll
        for (int off = 1; off < 64; off <<= 1) {
            ps  += __shfl_xor(ps,  off);
            ps2 += __shfl_xor(ps2, off);
        }
        float* red = tbuf;
        if (l == 0) { red[w*2] = ps; red[w*2+1] = ps2; }
        __syncthreads();
        if (tid == 0) {
            cpart[b2*2]     = red[0] + red[2] + red[4] + red[6];
            cpart[b2*2 + 1] = red[1] + red[3] + red[5] + red[7];
        }
        return;
    }
    if (blk < 1360) {                          // ---- transpose w_map -> wt[n][k] ----
        const int b2 = blk - 784;
        const int bn = (b2 % 24) * 32, bk = (b2 / 24) * 32;
        const int tx = tid & 31;
        float (*t)[33] = (float(*)[33])tbuf;
#pragma unroll
        for (int r = 0; r < 4; ++r) {
            int kk = (tid >> 5) * 4 + r;
            t[kk][tx] = w_map[(size_t)(bk + kk) * 768 + bn + tx];
        }
        __syncthreads();
#pragma unroll
        for (int r = 0; r < 4; ++r) {
            int nn = (tid >> 5) * 4 + r;
            wt[(size_t)(bn + nn) * 768 + bk + tx] = f2bf(t[tx][nn]);
        }
        return;
    }
    if (blk < 1396) {                          // ---- wqkv pre-transpose ----
        const int b3 = blk - 1360;
        const int h = b3 % 12, m = b3 / 12;
        const float* src = ((m == 0) ? wq : (m == 1) ? wk : wv) + (size_t)h*4096;
        float (*t)[65] = (float(*)[65])tbuf;
#pragma unroll
        for (int i = 0; i < 4; ++i) {
            int d = (tid >> 4) + i*16, e4 = (tid & 15) * 4;
            float4 v = *(const float4*)(src + d*64 + e4);
            t[d][e4+0] = v.x; t[d][e4+1] = v.y; t[d][e4+2] = v.z; t[d][e4+3] = v.w;
        }
        __syncthreads();
        u16* dst = wTg + ((size_t)(m*NHH + h)) * 4096;
#pragma unroll
        for (int i = 0; i < 4; ++i) {
            int e = (tid >> 4) + i*16, d4 = (tid & 15) * 4;
            union { u16 u[4]; uint2 v2; } o;
            o.u[0] = f2bf(t[d4+0][e]); o.u[1] = f2bf(t[d4+1][e]);
            o.u[2] = f2bf(t[d4+2][e]); o.u[3] = f2bf(t[d4+3][e]);
            *(uint2*)(dst + e*64 + d4) = o.v2;
        }
        return;
    }
    {                                          // ---- conv images f32 -> bf16 ----
        const int i = (blk - 1396) * 256 + tid;
        const int n8 = MPATCH*768/8;
        if (i < n8) {
            float4 a = ((const float4*)images)[2*i];
            float4 b = ((const float4*)images)[2*i + 1];
            union { u16 u[8]; uint4 v; } r;
            r.u[0]=f2bf(a.x); r.u[1]=f2bf(a.y); r.u[2]=f2bf(a.z); r.u[3]=f2bf(a.w);
            r.u[4]=f2bf(b.x); r.u[5]=f2bf(b.y); r.u[6]=f2bf(b.z); r.u[7]=f2bf(b.w);
            ((uint4*)imb)[i] = r.v;
        }
        return;
    }
}

// ---------------- MFMA GEMM (embed), 64x128 tile, XCD-chunked 1-D grid ----------------
__global__ __launch_bounds__(256) void gemm_mfma0(const u16* __restrict__ A,
        const u16* __restrict__ BT, const float* __restrict__ bias,
        const float* __restrict__ pos, u16* __restrict__ outp,
        float* __restrict__ gpart) {
    __shared__ u16 As[2][2048];   // [64 rows][32 k] bf16
    __shared__ u16 Bs[2][4096];   // [128 n][32 k]
    __shared__ float redg[16];
    const int tid = threadIdx.x;
    const int wv = tid >> 6, ln = tid & 63;
    const int bidr = blockIdx.x;
    const int logical = (bidr & 7) * 147 + (bidr >> 3);
    const int by = logical / 196, bx = logical - by * 196;
    const int m0 = bx * 64, n0 = by * 128;
    const int wr = wv >> 1, wc = wv & 1;      // wave -> 32 rows x 64 cols
    const int lrow = ln & 15, lk = ln >> 4;
    const int s0 = m0 / 196;

    f32x4 acc[2][4];
#pragma unroll
    for (int i = 0; i < 2; ++i)
#pragma unroll
        for (int j = 0; j < 4; ++j) acc[i][j] = (f32x4){0.f, 0.f, 0.f, 0.f};

    auto stageA = [&](u16* lbase, int k0) {
        int row = m0 + (tid >> 2);
        const void* g = (const char*)A + ((size_t)row * 768 + k0) * 2 + ((tid & 3) << 4);
        void* l = (char*)lbase + wv * 1024;
        __builtin_amdgcn_global_load_lds(
            (const __attribute__((address_space(1))) unsigned int*)g,
            (__attribute__((address_space(3))) unsigned int*)l, 16, 0, 0);
    };
    auto stageB = [&](u16* lbase, int k0) {
#pragma unroll
        for (int rep = 0; rep < 2; ++rep) {
            int c = rep * 256 + wv * 64 + ln;
            int row = n0 + (c >> 2);
            const void* g = (const char*)BT + ((size_t)row * 768 + k0) * 2 + ((c & 3) << 4);
            void* l = (char*)lbase + rep * 4096 + wv * 1024;
            __builtin_amdgcn_global_load_lds(
                (const __attribute__((address_space(1))) unsigned int*)g,
                (__attribute__((address_space(3))) unsigned int*)l, 16, 0, 0);
        }
    };

    stageA(&As[0][0], 0);
    stageB(&Bs[0][0], 0);
    __syncthreads();

    int cur = 0;
    for (int t = 0; t < 24; ++t) {
        if (t < 23) {
            stageA(&As[cur ^ 1][0], (t + 1) * 32);
            stageB(&Bs[cur ^ 1][0], (t + 1) * 32);
        }
        bf16x8 af[2], bfr[4];
#pragma unroll
        for (int i = 0; i < 2; ++i)
            af[i]  = *(const bf16x8*)&As[cur][(wr * 32 + i * 16 + lrow) * 32 + lk * 8];
#pragma unroll
        for (int j = 0; j < 4; ++j)
            bfr[j] = *(const bf16x8*)&Bs[cur][(wc * 64 + j * 16 + lrow) * 32 + lk * 8];
#pragma unroll
        for (int i = 0; i < 2; ++i)
#pragma unroll
            for (int j = 0; j < 4; ++j)
                acc[i][j] = __builtin_amdgcn_mfma_f32_16x16x32_bf16(af[i], bfr[j], acc[i][j], 0, 0, 0);
        __syncthreads();
        cur ^= 1;
    }

    float psA = 0.f, ps2A = 0.f, psB = 0.f, ps2B = 0.f;
#pragma unroll
    for (int i = 0; i < 2; ++i) {
        int gm = m0 + wr * 32 + i * 16 + (ln >> 4) * 4;
#pragma unroll
        for (int r = 0; r < 4; ++r) {
            int gmr = gm + r;
            int bsmp = gmr / 196, p = gmr - bsmp * 196;
#pragma unroll
            for (int j = 0; j < 4; ++j) {
                int n = n0 + wc * 64 + j * 16 + (ln & 15);
                float v = acc[i][j][r] + bias[n] + pos[(size_t)(p + 1) * 768 + n];
                outp[(size_t)(gmr + bsmp + 1) * 768 + n] = f2bf(v);
                if (bsmp == s0) { psA += v; ps2A += v*v; }
                else            { psB += v; ps2B += v*v; }
            }
        }
    }
#pragma unroll
    for (int off = 1; off < 64; off <<= 1) {
        psA  += __shfl_xor(psA,  off);  ps2A += __shfl_xor(ps2A, off);
        psB  += __shfl_xor(psB,  off);  ps2B += __shfl_xor(ps2B, off);
    }
    __syncthreads();
    if (ln == 0) {
        redg[wv*4+0] = psA; redg[wv*4+1] = ps2A;
        redg[wv*4+2] = psB; redg[wv*4+3] = ps2B;
    }
    __syncthreads();
    if (tid == 0) {
        float a = redg[0]+redg[4]+redg[8]+redg[12];
        float b = redg[1]+redg[5]+redg[9]+redg[13];
        float c = redg[2]+redg[6]+redg[10]+redg[14];
        float d = redg[3]+redg[7]+redg[11]+redg[15];
        float* gp = gpart + (size_t)(bx*6 + by)*4;
        gp[0] = a; gp[1] = b; gp[2] = c; gp[3] = d;
    }
}

// ---------------- QKV via MFMA: T14 prefetch, 2 barriers, V direct-store from acc ----------------
__global__ __launch_bounds__(256) void qkv_mfma(const u16* __restrict__ tokens,
        const float* __restrict__ gpart, const float* __restrict__ cpart,
        const float* __restrict__ ln1_g, const float* __restrict__ ln1_b,
        const u16* __restrict__ wTg,
        const float* __restrict__ bq, const float* __restrict__ bk,
        const float* __restrict__ bv,
        u16* __restrict__ qb, u16* __restrict__ kb, u16* __restrict__ vT) {
    __shared__ u16 Xs[64*72];          // 9216 u16
    __shared__ u16 Ws[3*64*72];        // 13824 u16
    __shared__ float smu[2], srs[2];
    const int c0 = blockIdx.x * 64, h = blockIdx.y;
    const int tid = threadIdx.x;
    const int w = tid >> 6, ln = tid & 63;
    const int lrow = ln & 15, lk = ln >> 4;
    const int bbase = c0 / 197;

    // ---- prefetch X rows + LN params into registers (stat-independent) ----
    union { u16 u[8]; uint4 v; } ti[2];
    float4 g0p[2], g1p[2], b0p[2], b1p[2];
#pragma unroll
    for (int it = 0; it < 2; ++it) {
        int c2 = tid + it*256;
        int r = c2 >> 3, q8 = (c2 & 7) * 8;
        int t = c0 + r;
        int bb = t / 197, s = t - bb * 197;
        const u16* tp = tokens + (size_t)t*768 + h*64 + q8;
        const float* gp = ln1_g + (size_t)s*768 + h*64 + q8;
        const float* bp = ln1_b + (size_t)s*768 + h*64 + q8;
        ti[it].v = *(const uint4*)tp;
        g0p[it] = *(const float4*)gp; g1p[it] = *(const float4*)(gp+4);
        b0p[it] = *(const float4*)bp; b1p[it] = *(const float4*)(bp+4);
    }
    // ---- W stage (stat-independent, overlaps stat reduce) ----
#pragma unroll
    for (int it = 0; it < 6; ++it) {
        int idx = tid + it*256;
        int m = idx >> 9, rem = idx & 511;
        int e = rem >> 3, c8 = (rem & 7) * 8;
        *(uint4*)&Ws[m*4608 + e*72 + c8] =
            *(const uint4*)(wTg + ((size_t)(m*NHH + h))*4096 + e*64 + c8);
    }

    // ---- LN1 stats for the (<=2) samples this chunk spans (unchanged mapping) ----
    if (w < 2) {
        int bb = bbase + w; if (bb > 63) bb = 63;
        int bx_lo = (bb == 0) ? 0 : (196*(bb-1) + 63) / 64;
        int bx_hi = (196*bb + 195) / 64; if (bx_hi > 195) bx_hi = 195;
        int nbx = bx_hi - bx_lo + 1;
        float s1 = 0.f, s2 = 0.f;
        if (ln < nbx * 6) {
            int bx = bx_lo + ln / 6, byi = ln % 6;
            const float* gp = gpart + (size_t)(bx*6 + byi)*4;
            int sA = (bx * 64) / 196;
            if (sA == bb)     { s1 += gp[0]; s2 += gp[1]; }
            if (sA + 1 == bb) { s1 += gp[2]; s2 += gp[3]; }
        }
        if (ln < 3) {
            s1 += cpart[(bb*3 + ln)*2];
            s2 += cpart[(bb*3 + ln)*2 + 1];
        }
#pragma unroll
        for (int off = 1; off < 64; off <<= 1) {
            s1 += __shfl_xor(s1, off);
            s2 += __shfl_xor(s2, off);
        }
        if (ln == 0) {
            float mu = s1 * (1.f / (float)LNN);
            float var = s2 * (1.f / (float)LNN) - mu*mu;
            smu[w] = mu;
            srs[w] = rsqrtf(var + 1e-5f);
        }
    }
    __syncthreads();                           // bar1: stats visible

    // ---- X: LN math from prefetched regs -> LDS ----
#pragma unroll
    for (int it = 0; it < 2; ++it) {
        int c2 = tid + it*256;
        int r = c2 >> 3, q8 = (c2 & 7) * 8;
        int t = c0 + r;
        int bb = t / 197;
        float mu = smu[bb - bbase];
        float rstd = srs[bb - bbase];
        union { u16 u[8]; uint4 v; } o;
        o.u[0] = f2bf((bf2f(ti[it].u[0]) - mu)*rstd*g0p[it].x + b0p[it].x);
        o.u[1] = f2bf((bf2f(ti[it].u[1]) - mu)*rstd*g0p[it].y + b0p[it].y);
        o.u[2] = f2bf((bf2f(ti[it].u[2]) - mu)*rstd*g0p[it].z + b0p[it].z);
        o.u[3] = f2bf((bf2f(ti[it].u[3]) - mu)*rstd*g0p[it].w + b0p[it].w);
        o.u[4] = f2bf((bf2f(ti[it].u[4]) - mu)*rstd*g1p[it].x + b1p[it].x);
        o.u[5] = f2bf((bf2f(ti[it].u[5]) - mu)*rstd*g1p[it].y + b1p[it].y);
        o.u[6] = f2bf((bf2f(ti[it].u[6]) - mu)*rstd*g1p[it].z + b1p[it].z);
        o.u[7] = f2bf((bf2f(ti[it].u[7]) - mu)*rstd*g1p[it].w + b1p[it].w);
        *(uint4*)&Xs[r*72 + q8] = o.v;
    }
    __syncthreads();                           // bar2: X + W in LDS

    bf16x8 af[2];
    af[0] = *(const bf16x8*)&Xs[(w*16 + lrow)*72 + lk*8];
    af[1] = *(const bf16x8*)&Xs[(w*16 + lrow)*72 + 32 + lk*8];
    f32x4 acc[3][4];
#pragma unroll
    for (int m = 0; m < 3; ++m)
#pragma unroll
        for (int j = 0; j < 4; ++j) acc[m][j] = (f32x4){0.f,0.f,0.f,0.f};
    __builtin_amdgcn_s_setprio(1);
#pragma unroll
    for (int m = 0; m < 3; ++m)
#pragma unroll
        for (int s = 0; s < 2; ++s)
#pragma unroll
            for (int j = 0; j < 4; ++j) {
                bf16x8 bfr = *(const bf16x8*)&Ws[m*4608 + (j*16 + lrow)*72 + s*32 + lk*8];
                acc[m][j] = __builtin_amdgcn_mfma_f32_16x16x32_bf16(af[s], bfr, acc[m][j], 0, 0, 0);
            }
    __builtin_amdgcn_s_setprio(0);

#pragma unroll
    for (int m = 0; m < 2; ++m) {
        const float* bias = ((m == 0) ? bq : bk) + h*64;
        u16* dst = (m == 0) ? qb : kb;
        float bj[4];
#pragma unroll
        for (int j = 0; j < 4; ++j) bj[j] = bias[j*16 + lrow];
#pragma unroll
        for (int r = 0; r < 4; ++r) {
            int t = c0 + w*16 + lk*4 + r;
            size_t o = (size_t)t*768 + h*64;
#pragma unroll
            for (int j = 0; j < 4; ++j)
                dst[o + j*16 + lrow] = f2bf(acc[m][j][r] + bj[j]);
        }
    }

    // ---- V: direct store from acc (acc layout == vT layout; no LDS, no barriers) ----
    {
        float bj[4];
#pragma unroll
        for (int j = 0; j < 4; ++j) bj[j] = bv[h*64 + j*16 + lrow];
        const int tb0 = c0 + w*16 + lk*4;      // this lane's first token (r=0)
#pragma unroll
        for (int j = 0; j < 4; ++j) {
            int d = j*16 + lrow;
#pragma unroll
            for (int r = 0; r < 4; ++r) {
                int t = tb0 + r;
                int bb = t / 197, s = t - bb * 197;
                vT[((size_t)(bb*NHH + h)*64 + d)*SQP + s] = f2bf(acc[2][j][r] + bj[j]);
            }
        }
    }
}

// ---------------- attention: Q-in-regs, register epilogue (no LDS transpose) ----------------
// 1-D grid 1536 with XCD-chunked swizzle: both q-halves of a (b,h) land on the same XCD.
__global__ __launch_bounds__(256) void attn_mfma(const u16* __restrict__ qb,
        const u16* __restrict__ kb, const u16* __restrict__ vT,
        const u16* __restrict__ tokens, float* __restrict__ cls_out,
        float* __restrict__ part2) {
    __shared__ u16 sh[9216];                  // Q-stage[128][72] -> Ks[64][72]|VTs[64][72]
    __shared__ float redp[8];

    const int bid = blockIdx.x;
    const int logical = (bid & 7) * 192 + (bid >> 3);   // 1536 = 8 XCD chunks x 192
    const int bh = logical >> 1;
    const int b = bh / NHH, h = bh % NHH;
    const int q0 = (logical & 1) * 128;
    const int tid = threadIdx.x;
    const int w = tid >> 6, l = tid & 63;
    const int g = l >> 4, lq = l & 15;

    {
        const u16* qbase = qb + (size_t)(b*197)*768 + h*64;
#pragma unroll
        for (int it = 0; it < 8; ++it) {
            int idx = tid + it*256;
            int r = idx >> 4, c = idx & 15;
            int gr = q0 + r; if (gr > 196) gr = 196;
            *(uint2*)&sh[r*72 + c*4] = *(const uint2*)(qbase + (size_t)gr*768 + c*4);
        }
    }
    __syncthreads();
    bf16x8 qfr[2][2];
#pragma unroll
    for (int s2 = 0; s2 < 2; ++s2)
#pragma unroll
        for (int s = 0; s < 2; ++s)
            qfr[s2][s] = *(const bf16x8*)&sh[(s2*64 + w*16 + lq)*72 + s*32 + g*8];

    u16* Ks  = sh;
    u16* VTs = sh + 4608;

    f32x4 acco[2][4];
#pragma unroll
    for (int s2 = 0; s2 < 2; ++s2)
#pragma unroll
        for (int i = 0; i < 4; ++i) acco[s2][i] = (f32x4){0.f,0.f,0.f,0.f};
    float S[2] = {0.f, 0.f};

    const int srcA = lq + ((l & 16) ? 32 : 0);
    const u16* krow = kb + (size_t)(b*197)*768 + h*64;
    const u16* vbase = vT + (size_t)bh*64*SQP;

    uint2 kreg[4], vreg[4];
    auto issueKV = [&](int tt) {
        const int t0 = tt * 64;
#pragma unroll
        for (int it = 0; it < 4; ++it) {
            int idx = tid + it*256;
            int r = idx >> 4, c = idx & 15;
            int gt = t0 + r; if (gt > 196) gt = 196;
            kreg[it] = *(const uint2*)(krow + (size_t)gt*768 + c*4);
            vreg[it] = *(const uint2*)(vbase + (size_t)r*SQP + t0 + c*4);
        }
    };
    issueKV(0);

    for (int tt = 0; tt < 4; ++tt) {
        __syncthreads();
#pragma unroll
        for (int it = 0; it < 4; ++it) {
            int idx = tid + it*256;
            int r = idx >> 4, c = idx & 15;
            *(uint2*)&Ks[r*72 + c*4]  = kreg[it];
            *(uint2*)&VTs[r*72 + c*4] = vreg[it];
        }
        if (tt < 3) issueKV(tt + 1);
        __syncthreads();

        const int t0 = tt * 64;
#pragma unroll
        for (int s2 = 0; s2 < 2; ++s2) {
            f32x4 accp[4];
#pragma unroll
            for (int i = 0; i < 4; ++i) accp[i] = (f32x4){0.f,0.f,0.f,0.f};
            __builtin_amdgcn_s_setprio(1);
#pragma unroll
            for (int s = 0; s < 2; ++s) {
#pragma unroll
                for (int tb = 0; tb < 4; ++tb) {
                    bf16x8 kf = *(const bf16x8*)&Ks[(tb*16 + lq)*72 + s*32 + g*8];
                    accp[tb] = __builtin_amdgcn_mfma_f32_16x16x32_bf16(kf, qfr[s2][s], accp[tb], 0, 0, 0);
                }
            }
            __builtin_amdgcn_s_setprio(0);

            unsigned pk[4][2];
#pragma unroll
            for (int tb = 0; tb < 4; ++tb) {
                int tbase = t0 + tb*16 + g*4;
                float p0 = (tbase + 0 < 197) ? __expf(accp[tb][0] * 0.125f) : 0.f;
                float p1 = (tbase + 1 < 197) ? __expf(accp[tb][1] * 0.125f) : 0.f;
                float p2 = (tbase + 2 < 197) ? __expf(accp[tb][2] * 0.125f) : 0.f;
                float p3 = (tbase + 3 < 197) ? __expf(accp[tb][3] * 0.125f) : 0.f;
                S[s2] += (p0 + p1) + (p2 + p3);
                asm("v_cvt_pk_bf16_f32 %0, %1, %2" : "=v"(pk[tb][0]) : "v"(p0), "v"(p1));
                asm("v_cvt_pk_bf16_f32 %0, %1, %2" : "=v"(pk[tb][1]) : "v"(p2), "v"(p3));
            }

#pragma unroll
            for (int s = 0; s < 2; ++s) {
                union { unsigned u[4]; bf16x8 v; } bp;
#pragma unroll
                for (int c = 0; c < 4; ++c) {
                    int src = srcA + ((c >= 2) ? 16 : 0);
                    unsigned v0 = (unsigned)__shfl((int)pk[2*s + 0][c & 1], src);
                    unsigned v1 = (unsigned)__shfl((int)pk[2*s + 1][c & 1], src);
                    bp.u[c] = (l & 32) ? v1 : v0;
                }
                __builtin_amdgcn_s_setprio(1);
#pragma unroll
                for (int dblk = 0; dblk < 4; ++dblk) {
                    bf16x8 vf = *(const bf16x8*)&VTs[(dblk*16 + lq)*72 + s*32 + g*8];
                    acco[s2][dblk] = __builtin_amdgcn_mfma_f32_16x16x32_bf16(vf, bp.v, acco[s2][dblk], 0, 0, 0);
                }
                __builtin_amdgcn_s_setprio(0);
            }
        }
    }

    float invS[2];
#pragma unroll
    for (int s2 = 0; s2 < 2; ++s2) {
        S[s2] += __shfl_xor(S[s2], 16);
        S[s2] += __shfl_xor(S[s2], 32);
        invS[s2] = 1.f / S[s2];
    }

    // register epilogue: lane's acco covers fixed q row (q0+s2*64+w*16+lq),
    // d = dblk*16 + g*4 + r (4 consecutive per dblk). Stats + cls write direct.
    float ps = 0.f, ps2v = 0.f;
#pragma unroll
    for (int s2 = 0; s2 < 2; ++s2) {
        const int q_glob = q0 + s2*64 + w*16 + lq;
        if (q_glob < 197) {
            const u16* trow = tokens + (size_t)(b*197 + q_glob)*768 + h*64;
            float* crow = cls_out + (size_t)b*768 + h*64;
#pragma unroll
            for (int dblk = 0; dblk < 4; ++dblk) {
                int d0 = dblk*16 + g*4;
                union { u16 u[4]; uint2 v; } tb_;
                tb_.v = *(const uint2*)(trow + d0);
                float4 t;
                t.x = bf2f(tb_.u[0]) + acco[s2][dblk][0] * invS[s2];
                t.y = bf2f(tb_.u[1]) + acco[s2][dblk][1] * invS[s2];
                t.z = bf2f(tb_.u[2]) + acco[s2][dblk][2] * invS[s2];
                t.w = bf2f(tb_.u[3]) + acco[s2][dblk][3] * invS[s2];
                ps   += (t.x + t.y) + (t.z + t.w);
                ps2v += (t.x*t.x + t.y*t.y) + (t.z*t.z + t.w*t.w);
                if (q_glob == 0) *(float4*)(crow + d0) = t;
            }
        }
    }

#pragma unroll
    for (int off = 1; off < 64; off <<= 1) {
        ps   += __shfl_xor(ps,   off);
        ps2v += __shfl_xor(ps2v, off);
    }
    if (l == 0) { redp[w*2] = ps; redp[w*2 + 1] = ps2v; }
    __syncthreads();
    if (tid == 0) {
        float a = redp[0] + redp[2] + redp[4] + redp[6];
        float c = redp[1] + redp[3] + redp[5] + redp[7];
        part2[logical*2]     = a;             // slot = bh*2 + half
        part2[logical*2 + 1] = c;
    }
}

// ---------------- MLP(cls) k-split partials: grid (16 bgroups, 3 o-tiles, 8 k-slices) ----------------
__global__ __launch_bounds__(256) void mlp_part(const float* __restrict__ cls_out,
        const float* __restrict__ part2, const float* __restrict__ ln2_g,
        const float* __restrict__ ln2_b, const float* __restrict__ w_enc,
        float* __restrict__ mpart) {
    __shared__ float y0[4][96];
    __shared__ float mu4[4], rs4[4];
    const int bg = blockIdx.x;                // samples 4bg..4bg+3
    const int n  = blockIdx.y * 256 + threadIdx.x;
    const int ks = blockIdx.z;
    const int k0 = ks * 96;
    if (threadIdx.x < 4) {
        int b = bg*4 + threadIdx.x;
        float s1 = 0.f, s2 = 0.f;
        for (int i = 0; i < 24; ++i) {
            s1 += part2[(b*24 + i)*2];
            s2 += part2[(b*24 + i)*2 + 1];
        }
        float mu = s1 * (1.f / (float)LNN);
        float var = s2 * (1.f / (float)LNN) - mu*mu;
        mu4[threadIdx.x] = mu;
        rs4[threadIdx.x] = rsqrtf(var + 1e-5f);
    }
    __syncthreads();
    if (threadIdx.x < 96) {
        int k = k0 + threadIdx.x;
        float gk = ln2_g[k], bk_ = ln2_b[k];
#pragma unroll
        for (int i = 0; i < 4; ++i) {
            float c = cls_out[(size_t)(bg*4 + i)*768 + k];
            y0[i][threadIdx.x] = (c - mu4[i]) * rs4[i] * gk + bk_;
        }
    }
    __syncthreads();
    if (n < 768) {
        float a0 = 0.f, a1 = 0.f, a2 = 0.f, a3 = 0.f;
#pragma unroll 8
        for (int k = 0; k < 96; ++k) {
            float wv = w_enc[(size_t)(k0 + k)*768 + n];
            a0 += y0[0][k] * wv;
            a1 += y0[1][k] * wv;
            a2 += y0[2][k] * wv;
            a3 += y0[3][k] * wv;
        }
        mpart[((size_t)(bg*4 + 0)*8 + ks)*768 + n] = a0;
        mpart[((size_t)(bg*4 + 1)*8 + ks)*768 + n] = a1;
        mpart[((size_t)(bg*4 + 2)*8 + ks)*768 + n] = a2;
        mpart[((size_t)(bg*4 + 3)*8 + ks)*768 + n] = a3;
    }
}

// ---------------- head: fused mlp_fin + logits partials ----------------
__global__ __launch_bounds__(256) void logits_kernel(const float* __restrict__ mpart,
        const float* __restrict__ b_enc, const float* __restrict__ cls_out,
        const float* __restrict__ w_head, float* __restrict__ lpart) {
    __shared__ float xr[4][96];
    const int bg = blockIdx.x;                // 16 -> samples 4bg..4bg+3
    const int o  = blockIdx.y * 256 + threadIdx.x;
    const int ks = blockIdx.z;                // 8 -> k0 = 96*ks
    const int k0 = ks * 96;
    if (threadIdx.x < 96) {
        int k = k0 + threadIdx.x;
        float be = b_enc[k];
#pragma unroll
        for (int i = 0; i < 4; ++i) {
            int b = bg*4 + i;
            float a = be;
#pragma unroll
            for (int ks2 = 0; ks2 < 8; ++ks2)
                a += mpart[((size_t)b*8 + ks2)*768 + k];
            xr[i][threadIdx.x] = cls_out[(size_t)b*768 + k] + fmaxf(a, 0.f);
        }
    }
    __syncthreads();
    if (o < NOUT) {
        float a0 = 0.f, a1 = 0.f, a2 = 0.f, a3 = 0.f;
#pragma unroll 8
        for (int k = 0; k < 96; ++k) {
            float wv = w_head[(size_t)(k0 + k)*NOUT + o];
            a0 += xr[0][k] * wv;
            a1 += xr[1][k] * wv;
            a2 += xr[2][k] * wv;
            a3 += xr[3][k] * wv;
        }
        lpart[((size_t)(bg*4 + 0)*8 + ks)*NOUT + o] = a0;
        lpart[((size_t)(bg*4 + 1)*8 + ks)*NOUT + o] = a1;
        lpart[((size_t)(bg*4 + 2)*8 + ks)*NOUT + o] = a2;
        lpart[((size_t)(bg*4 + 3)*8 + ks)*NOUT + o] = a3;
    }
}

__global__ __launch_bounds__(256) void softmax_kernel(const float* __restrict__ lpart,
        const float* __restrict__ b_head, float* __restrict__ outp) {
    __shared__ float red[8];
    const int b = blockIdx.x, tid = threadIdx.x;
    const int w = tid >> 6, l = tid & 63;
    float v[4];
    float mx = -1e30f;
#pragma unroll
    for (int i = 0; i < 4; ++i) {
        int t = tid + i*256;
        if (t < NOUT) {
            float a = b_head[t];
#pragma unroll
            for (int ks = 0; ks < 8; ++ks)
                a += lpart[((size_t)b*8 + ks)*NOUT + t];
            v[i] = a;
        } else v[i] = -1e30f;
        mx = fmaxf(mx, v[i]);
    }
    for (int off = 32; off; off >>= 1) mx = fmaxf(mx, __shfl_xor(mx, off));
    if (l == 0) red[w] = mx;
    __syncthreads();
    if (tid == 0) red[4] = fmaxf(fmaxf(red[0], red[1]), fmaxf(red[2], red[3]));
    __syncthreads();
    const float m = red[4];
    float s = 0.f;
#pragma unroll
    for (int i = 0; i < 4; ++i) { v[i] = __expf(v[i] - m); s += v[i]; }
    for (int off = 32; off; off >>= 1) s += __shfl_xor(s, off);
    if (l == 0) red[w] = s;
    __syncthreads();
    if (tid == 0) red[5] = red[0] + red[1] + red[2] + red[3];
    __syncthreads();
    const float inv = 1.f / red[5];
#pragma unroll
    for (int i = 0; i < 4; ++i) {
        int t = tid + i*256;
        if (t < NOUT) outp[(size_t)b*NOUT + t] = v[i] * inv;
    }
}

// ---------------- launch ----------------
extern "C" void kernel_launch(void* const* d_in, const int* in_sizes, int n_in,
                              void* d_out, int out_size, void* d_ws, size_t ws_size,
                              hipStream_t stream) {
    (void)in_sizes; (void)n_in; (void)out_size; (void)ws_size;
    const float* images = (const float*)d_in[0];
    const float* w_map  = (const float*)d_in[1];
    const float* b_map  = (const float*)d_in[2];
    const float* cls_tok= (const float*)d_in[3];
    const float* ln1_g  = (const float*)d_in[4];
    const float* ln1_b  = (const float*)d_in[5];
    const float* wq     = (const float*)d_in[6];
    const float* bq     = (const float*)d_in[7];
    const float* wk     = (const float*)d_in[8];
    const float* bk     = (const float*)d_in[9];
    const float* wv     = (const float*)d_in[10];
    const float* bv     = (const float*)d_in[11];
    const float* ln2_g  = (const float*)d_in[12];
    const float* ln2_b  = (const float*)d_in[13];
    const float* w_enc  = (const float*)d_in[14];
    const float* b_enc  = (const float*)d_in[15];
    const float* w_head = (const float*)d_in[16];
    const float* b_head = (const float*)d_in[17];
    float* out = (float*)d_out;
    float* ws = (float*)d_ws;

    float* pos    = ws;                     // 151296
    float* tokens = pos + 151296;           // tokens_bf overlay (u16, 19.4 MB used of slot)
    float* x      = tokens + 9682944;       // spare (layout stability)
    float* q      = x + 9682944;            // imb overlay, then qb
    float* kk     = q + 9682944;            // wt(w_map) overlay, then kb
    float* vv     = kk + 9682944;           // vT bf16 [768][64][256]
    float* part   = vv + 9682944;           // 512 (spare)
    float* part2  = part + 512;             // 3072 (ln2 per-(b,h,qhalf) partials)
    float* mlp_o  = part2 + 3072;           // 49152 (spare)
    float* lpart  = mlp_o + 49152;          // 512000 (logit k-split partials)
    float* wqkvT  = lpart + 512000;         // 73728 f32-slots = 147456 u16 bf16
    float* gpart  = wqkvT + 73728;          // 4704 (gemm0 LN1 partials, 1176 groups)
    float* cpart  = gpart + 4704;           // 384 (cls LN1 partials)
    float* cls_o  = cpart + 384;            // 49152 (post-attn cls rows, f32)
    float* mpart  = cls_o + 49152;          // 393216 (mlp k-split partials)

    u16* tkb = (u16*)tokens;   // bf16 tokens (residual), L2-resident
    u16* imb = (u16*)q;
    u16* wt  = (u16*)kk;
    u16* qbp = (u16*)q;
    u16* kbp = (u16*)kk;
    u16* vTp = (u16*)vv;
    u16* wTg = (u16*)wqkvT;

    prep_kernel<<<6100, 256, 0, stream>>>(cls_tok, images, w_map, wq, wk, wv,
                                          pos, tkb, cpart, imb, wt, wTg);
    gemm_mfma0<<<1176, 256, 0, stream>>>(imb, wt, b_map, pos, tkb, gpart);
    qkv_mfma<<<dim3(197, NHH), 256, 0, stream>>>(tkb, gpart, cpart, ln1_g, ln1_b, wTg,
                                                 bq, bk, bv, qbp, kbp, vTp);
    attn_mfma<<<BB_*NHH*2, 256, 0, stream>>>(qbp, kbp, vTp, tkb, cls_o, part2);
    mlp_part<<<dim3(16, 3, 8), 256, 0, stream>>>(cls_o, part2, ln2_g, ln2_b, w_enc, mpart);
    logits_kernel<<<dim3(16, 4, 8), 256, 0, stream>>>(mpart, b_enc, cls_o, w_head, lpart);
    softmax_kernel<<<BB_, 256, 0, stream>>>(lpart, b_head, out);
}

// Round 27
// 123.608 us; speedup vs baseline: 1.0920x; 1.0920x over previous
//
#include <hip/hip_runtime.h>
#include <math.h>

// ---------------- dims ----------------
#define SQ 197           // tokens
#define DD 768           // hidden
#define NHH 12
#define DHH 64
#define BB_ 64           // batch
#define MTOK (BB_*SQ)    // 12608
#define MPATCH (BB_*196) // 12544
#define NOUT 1000
#define LNN (SQ*DD)      // 151296 elems per sample
#define SQP 256          // padded seq for vT

typedef unsigned short u16;
typedef __attribute__((ext_vector_type(8))) short bf16x8;
typedef __attribute__((ext_vector_type(4))) float f32x4;

__device__ __forceinline__ u16 f2bf(float x) {      // RNE f32->bf16
    unsigned u = __float_as_uint(x);
    u = (u + 0x7FFF + ((u >> 16) & 1)) >> 16;
    return (u16)u;
}
__device__ __forceinline__ float bf2f(u16 x) {
    return __uint_as_float(((unsigned)x) << 16);
}

// ---------------- fused prologue: pos_emb | cls | transpose(w_map) | wqkv_prep | conv ----------------
__global__ __launch_bounds__(256) void prep_kernel(
        const float* __restrict__ cls_tok, const float* __restrict__ images,
        const float* __restrict__ w_map,
        const float* __restrict__ wq, const float* __restrict__ wk,
        const float* __restrict__ wv,
        float* __restrict__ pos, u16* __restrict__ tokens,
        float* __restrict__ cpart, u16* __restrict__ imb,
        u16* __restrict__ wt, u16* __restrict__ wTg) {
    __shared__ float tbuf[64*65];              // 16.6 KB, aliased per branch
    const int blk = blockIdx.x, tid = threadIdx.x;

    if (blk < 592) {                           // ---- pos_emb ----
        int i = blk * 256 + tid;
        if (i < SQ * DD) {
            int s = i / DD, d = i % DD;
            double e = (double)(d & ~1) / (double)DD;
            double ang = (double)s * pow(10000.0, -e);
            pos[i] = (d & 1) ? (float)cos(ang) : (float)sin(ang);
        }
        return;
    }
    if (blk < 784) {                           // ---- cls + LN1 partials ----
        const int b2 = blk - 592;
        const int i = b2 * 256 + tid;
        const int b = i / DD, d = i % DD;
        float v = cls_tok[d] + ((d & 1) ? 1.0f : 0.0f);
        tokens[(size_t)b * SQ * DD + d] = f2bf(v);
        float ps = v, ps2 = v * v;
        const int w = tid >> 6, l = tid & 63;
#pragma unroll
        for (int off = 1; off < 64; off <<= 1) {
            ps  += __shfl_xor(ps,  off);
            ps2 += __shfl_xor(ps2, off);
        }
        float* red = tbuf;
        if (l == 0) { red[w*2] = ps; red[w*2+1] = ps2; }
        __syncthreads();
        if (tid == 0) {
            cpart[b2*2]     = red[0] + red[2] + red[4] + red[6];
            cpart[b2*2 + 1] = red[1] + red[3] + red[5] + red[7];
        }
        return;
    }
    if (blk < 1360) {                          // ---- transpose w_map -> wt[n][k] ----
        const int b2 = blk - 784;
        const int bn = (b2 % 24) * 32, bk = (b2 / 24) * 32;
        const int tx = tid & 31;
        float (*t)[33] = (float(*)[33])tbuf;
#pragma unroll
        for (int r = 0; r < 4; ++r) {
            int kk = (tid >> 5) * 4 + r;
            t[kk][tx] = w_map[(size_t)(bk + kk) * 768 + bn + tx];
        }
        __syncthreads();
#pragma unroll
        for (int r = 0; r < 4; ++r) {
            int nn = (tid >> 5) * 4 + r;
            wt[(size_t)(bn + nn) * 768 + bk + tx] = f2bf(t[tx][nn]);
        }
        return;
    }
    if (blk < 1396) {                          // ---- wqkv pre-transpose ----
        const int b3 = blk - 1360;
        const int h = b3 % 12, m = b3 / 12;
        const float* src = ((m == 0) ? wq : (m == 1) ? wk : wv) + (size_t)h*4096;
        float (*t)[65] = (float(*)[65])tbuf;
#pragma unroll
        for (int i = 0; i < 4; ++i) {
            int d = (tid >> 4) + i*16, e4 = (tid & 15) * 4;
            float4 v = *(const float4*)(src + d*64 + e4);
            t[d][e4+0] = v.x; t[d][e4+1] = v.y; t[d][e4+2] = v.z; t[d][e4+3] = v.w;
        }
        __syncthreads();
        u16* dst = wTg + ((size_t)(m*NHH + h)) * 4096;
#pragma unroll
        for (int i = 0; i < 4; ++i) {
            int e = (tid >> 4) + i*16, d4 = (tid & 15) * 4;
            union { u16 u[4]; uint2 v2; } o;
            o.u[0] = f2bf(t[d4+0][e]); o.u[1] = f2bf(t[d4+1][e]);
            o.u[2] = f2bf(t[d4+2][e]); o.u[3] = f2bf(t[d4+3][e]);
            *(uint2*)(dst + e*64 + d4) = o.v2;
        }
        return;
    }
    {                                          // ---- conv images f32 -> bf16 ----
        const int i = (blk - 1396) * 256 + tid;
        const int n8 = MPATCH*768/8;
        if (i < n8) {
            float4 a = ((const float4*)images)[2*i];
            float4 b = ((const float4*)images)[2*i + 1];
            union { u16 u[8]; uint4 v; } r;
            r.u[0]=f2bf(a.x); r.u[1]=f2bf(a.y); r.u[2]=f2bf(a.z); r.u[3]=f2bf(a.w);
            r.u[4]=f2bf(b.x); r.u[5]=f2bf(b.y); r.u[6]=f2bf(b.z); r.u[7]=f2bf(b.w);
            ((uint4*)imb)[i] = r.v;
        }
        return;
    }
}

// ---------------- MFMA GEMM (embed), 64x128 tile, XCD-chunked 1-D grid ----------------
__global__ __launch_bounds__(256) void gemm_mfma0(const u16* __restrict__ A,
        const u16* __restrict__ BT, const float* __restrict__ bias,
        const float* __restrict__ pos, u16* __restrict__ outp,
        float* __restrict__ gpart) {
    __shared__ u16 As[2][2048];   // [64 rows][32 k] bf16
    __shared__ u16 Bs[2][4096];   // [128 n][32 k]
    __shared__ float redg[16];
    const int tid = threadIdx.x;
    const int wv = tid >> 6, ln = tid & 63;
    const int bidr = blockIdx.x;
    const int logical = (bidr & 7) * 147 + (bidr >> 3);
    const int by = logical / 196, bx = logical - by * 196;
    const int m0 = bx * 64, n0 = by * 128;
    const int wr = wv >> 1, wc = wv & 1;      // wave -> 32 rows x 64 cols
    const int lrow = ln & 15, lk = ln >> 4;
    const int s0 = m0 / 196;

    f32x4 acc[2][4];
#pragma unroll
    for (int i = 0; i < 2; ++i)
#pragma unroll
        for (int j = 0; j < 4; ++j) acc[i][j] = (f32x4){0.f, 0.f, 0.f, 0.f};

    auto stageA = [&](u16* lbase, int k0) {
        int row = m0 + (tid >> 2);
        const void* g = (const char*)A + ((size_t)row * 768 + k0) * 2 + ((tid & 3) << 4);
        void* l = (char*)lbase + wv * 1024;
        __builtin_amdgcn_global_load_lds(
            (const __attribute__((address_space(1))) unsigned int*)g,
            (__attribute__((address_space(3))) unsigned int*)l, 16, 0, 0);
    };
    auto stageB = [&](u16* lbase, int k0) {
#pragma unroll
        for (int rep = 0; rep < 2; ++rep) {
            int c = rep * 256 + wv * 64 + ln;
            int row = n0 + (c >> 2);
            const void* g = (const char*)BT + ((size_t)row * 768 + k0) * 2 + ((c & 3) << 4);
            void* l = (char*)lbase + rep * 4096 + wv * 1024;
            __builtin_amdgcn_global_load_lds(
                (const __attribute__((address_space(1))) unsigned int*)g,
                (__attribute__((address_space(3))) unsigned int*)l, 16, 0, 0);
        }
    };

    stageA(&As[0][0], 0);
    stageB(&Bs[0][0], 0);
    __syncthreads();

    int cur = 0;
    for (int t = 0; t < 24; ++t) {
        if (t < 23) {
            stageA(&As[cur ^ 1][0], (t + 1) * 32);
            stageB(&Bs[cur ^ 1][0], (t + 1) * 32);
        }
        bf16x8 af[2], bfr[4];
#pragma unroll
        for (int i = 0; i < 2; ++i)
            af[i]  = *(const bf16x8*)&As[cur][(wr * 32 + i * 16 + lrow) * 32 + lk * 8];
#pragma unroll
        for (int j = 0; j < 4; ++j)
            bfr[j] = *(const bf16x8*)&Bs[cur][(wc * 64 + j * 16 + lrow) * 32 + lk * 8];
#pragma unroll
        for (int i = 0; i < 2; ++i)
#pragma unroll
            for (int j = 0; j < 4; ++j)
                acc[i][j] = __builtin_amdgcn_mfma_f32_16x16x32_bf16(af[i], bfr[j], acc[i][j], 0, 0, 0);
        __syncthreads();
        cur ^= 1;
    }

    float psA = 0.f, ps2A = 0.f, psB = 0.f, ps2B = 0.f;
#pragma unroll
    for (int i = 0; i < 2; ++i) {
        int gm = m0 + wr * 32 + i * 16 + (ln >> 4) * 4;
#pragma unroll
        for (int r = 0; r < 4; ++r) {
            int gmr = gm + r;
            int bsmp = gmr / 196, p = gmr - bsmp * 196;
#pragma unroll
            for (int j = 0; j < 4; ++j) {
                int n = n0 + wc * 64 + j * 16 + (ln & 15);
                float v = acc[i][j][r] + bias[n] + pos[(size_t)(p + 1) * 768 + n];
                outp[(size_t)(gmr + bsmp + 1) * 768 + n] = f2bf(v);
                if (bsmp == s0) { psA += v; ps2A += v*v; }
                else            { psB += v; ps2B += v*v; }
            }
        }
    }
#pragma unroll
    for (int off = 1; off < 64; off <<= 1) {
        psA  += __shfl_xor(psA,  off);  ps2A += __shfl_xor(ps2A, off);
        psB  += __shfl_xor(psB,  off);  ps2B += __shfl_xor(ps2B, off);
    }
    __syncthreads();
    if (ln == 0) {
        redg[wv*4+0] = psA; redg[wv*4+1] = ps2A;
        redg[wv*4+2] = psB; redg[wv*4+3] = ps2B;
    }
    __syncthreads();
    if (tid == 0) {
        float a = redg[0]+redg[4]+redg[8]+redg[12];
        float b = redg[1]+redg[5]+redg[9]+redg[13];
        float c = redg[2]+redg[6]+redg[10]+redg[14];
        float d = redg[3]+redg[7]+redg[11]+redg[15];
        float* gp = gpart + (size_t)(bx*6 + by)*4;
        gp[0] = a; gp[1] = b; gp[2] = c; gp[3] = d;
    }
}

// ---------------- QKV via MFMA: T14 prefetch + W hoist, LDS-staged coalesced V scatter ----------------
__global__ __launch_bounds__(256) void qkv_mfma(const u16* __restrict__ tokens,
        const float* __restrict__ gpart, const float* __restrict__ cpart,
        const float* __restrict__ ln1_g, const float* __restrict__ ln1_b,
        const u16* __restrict__ wTg,
        const float* __restrict__ bq, const float* __restrict__ bk,
        const float* __restrict__ bv,
        u16* __restrict__ qb, u16* __restrict__ kb, u16* __restrict__ vT) {
    __shared__ u16 Xs[64*72];          // 9216 u16; reused as vstage
    __shared__ u16 Ws[3*64*72];        // 13824 u16
    __shared__ float smu[2], srs[2];
    const int c0 = blockIdx.x * 64, h = blockIdx.y;
    const int tid = threadIdx.x;
    const int w = tid >> 6, ln = tid & 63;
    const int lrow = ln & 15, lk = ln >> 4;
    const int bbase = c0 / 197;

    // ---- T14 prefetch: X rows + LN params into registers (stat-independent) ----
    union { u16 u[8]; uint4 v; } ti[2];
    float4 g0p[2], g1p[2], b0p[2], b1p[2];
#pragma unroll
    for (int it = 0; it < 2; ++it) {
        int c2 = tid + it*256;
        int r = c2 >> 3, q8 = (c2 & 7) * 8;
        int t = c0 + r;
        int bb = t / 197, s = t - bb * 197;
        const u16* tp = tokens + (size_t)t*768 + h*64 + q8;
        const float* gp = ln1_g + (size_t)s*768 + h*64 + q8;
        const float* bp = ln1_b + (size_t)s*768 + h*64 + q8;
        ti[it].v = *(const uint4*)tp;
        g0p[it] = *(const float4*)gp; g1p[it] = *(const float4*)(gp+4);
        b0p[it] = *(const float4*)bp; b1p[it] = *(const float4*)(bp+4);
    }
    // ---- W stage (stat-independent, overlaps stat reduce) ----
#pragma unroll
    for (int it = 0; it < 6; ++it) {
        int idx = tid + it*256;
        int m = idx >> 9, rem = idx & 511;
        int e = rem >> 3, c8 = (rem & 7) * 8;
        *(uint4*)&Ws[m*4608 + e*72 + c8] =
            *(const uint4*)(wTg + ((size_t)(m*NHH + h))*4096 + e*64 + c8);
    }

    // ---- LN1 stats for the (<=2) samples this chunk spans ----
    if (w < 2) {
        int bb = bbase + w; if (bb > 63) bb = 63;
        int bx_lo = (bb == 0) ? 0 : (196*(bb-1) + 63) / 64;
        int bx_hi = (196*bb + 195) / 64; if (bx_hi > 195) bx_hi = 195;
        int nbx = bx_hi - bx_lo + 1;
        float s1 = 0.f, s2 = 0.f;
        if (ln < nbx * 6) {
            int bx = bx_lo + ln / 6, byi = ln % 6;
            const float* gp = gpart + (size_t)(bx*6 + byi)*4;
            int sA = (bx * 64) / 196;
            if (sA == bb)     { s1 += gp[0]; s2 += gp[1]; }
            if (sA + 1 == bb) { s1 += gp[2]; s2 += gp[3]; }
        }
        if (ln < 3) {
            s1 += cpart[(bb*3 + ln)*2];
            s2 += cpart[(bb*3 + ln)*2 + 1];
        }
#pragma unroll
        for (int off = 1; off < 64; off <<= 1) {
            s1 += __shfl_xor(s1, off);
            s2 += __shfl_xor(s2, off);
        }
        if (ln == 0) {
            float mu = s1 * (1.f / (float)LNN);
            float var = s2 * (1.f / (float)LNN) - mu*mu;
            smu[w] = mu;
            srs[w] = rsqrtf(var + 1e-5f);
        }
    }
    __syncthreads();                           // bar1: stats visible

    // ---- X: LN math from prefetched regs -> LDS ----
#pragma unroll
    for (int it = 0; it < 2; ++it) {
        int c2 = tid + it*256;
        int r = c2 >> 3, q8 = (c2 & 7) * 8;
        int t = c0 + r;
        int bb = t / 197;
        float mu = smu[bb - bbase];
        float rstd = srs[bb - bbase];
        union { u16 u[8]; uint4 v; } o;
        o.u[0] = f2bf((bf2f(ti[it].u[0]) - mu)*rstd*g0p[it].x + b0p[it].x);
        o.u[1] = f2bf((bf2f(ti[it].u[1]) - mu)*rstd*g0p[it].y + b0p[it].y);
        o.u[2] = f2bf((bf2f(ti[it].u[2]) - mu)*rstd*g0p[it].z + b0p[it].z);
        o.u[3] = f2bf((bf2f(ti[it].u[3]) - mu)*rstd*g0p[it].w + b0p[it].w);
        o.u[4] = f2bf((bf2f(ti[it].u[4]) - mu)*rstd*g1p[it].x + b1p[it].x);
        o.u[5] = f2bf((bf2f(ti[it].u[5]) - mu)*rstd*g1p[it].y + b1p[it].y);
        o.u[6] = f2bf((bf2f(ti[it].u[6]) - mu)*rstd*g1p[it].z + b1p[it].z);
        o.u[7] = f2bf((bf2f(ti[it].u[7]) - mu)*rstd*g1p[it].w + b1p[it].w);
        *(uint4*)&Xs[r*72 + q8] = o.v;
    }
    __syncthreads();                           // bar2: X + W in LDS

    bf16x8 af[2];
    af[0] = *(const bf16x8*)&Xs[(w*16 + lrow)*72 + lk*8];
    af[1] = *(const bf16x8*)&Xs[(w*16 + lrow)*72 + 32 + lk*8];
    f32x4 acc[3][4];
#pragma unroll
    for (int m = 0; m < 3; ++m)
#pragma unroll
        for (int j = 0; j < 4; ++j) acc[m][j] = (f32x4){0.f,0.f,0.f,0.f};
    __builtin_amdgcn_s_setprio(1);
#pragma unroll
    for (int m = 0; m < 3; ++m)
#pragma unroll
        for (int s = 0; s < 2; ++s)
#pragma unroll
            for (int j = 0; j < 4; ++j) {
                bf16x8 bfr = *(const bf16x8*)&Ws[m*4608 + (j*16 + lrow)*72 + s*32 + lk*8];
                acc[m][j] = __builtin_amdgcn_mfma_f32_16x16x32_bf16(af[s], bfr, acc[m][j], 0, 0, 0);
            }
    __builtin_amdgcn_s_setprio(0);

#pragma unroll
    for (int m = 0; m < 2; ++m) {
        const float* bias = ((m == 0) ? bq : bk) + h*64;
        u16* dst = (m == 0) ? qb : kb;
        float bj[4];
#pragma unroll
        for (int j = 0; j < 4; ++j) bj[j] = bias[j*16 + lrow];
#pragma unroll
        for (int r = 0; r < 4; ++r) {
            int t = c0 + w*16 + lk*4 + r;
            size_t o = (size_t)t*768 + h*64;
#pragma unroll
            for (int j = 0; j < 4; ++j)
                dst[o + j*16 + lrow] = f2bf(acc[m][j][r] + bj[j]);
        }
    }

    // ---- V: LDS transpose stage -> coalesced scatter (restored from R25) ----
    {
        float bj[4];
#pragma unroll
        for (int j = 0; j < 4; ++j) bj[j] = bv[h*64 + j*16 + lrow];
        __syncthreads();
        u16* vs = Xs;                          // [64 e][72 tok]
#pragma unroll
        for (int j = 0; j < 4; ++j)
#pragma unroll
            for (int r = 0; r < 4; ++r)
                vs[(j*16 + lrow)*72 + (w*16 + lk*4 + r)] = f2bf(acc[2][j][r] + bj[j]);
        __syncthreads();
        for (int idx = tid; idx < 4096; idx += 256) {
            int d = idx >> 6, tl = idx & 63;
            int t = c0 + tl;
            int bb = t / 197, s = t - bb * 197;
            vT[((size_t)(bb*NHH + h)*64 + d)*SQP + s] = vs[d*72 + tl];
        }
    }
}

// ---------------- attention: Q-in-regs, register epilogue (no LDS transpose) ----------------
// 1-D grid 1536 with XCD-chunked swizzle: both q-halves of a (b,h) land on the same XCD.
__global__ __launch_bounds__(256) void attn_mfma(const u16* __restrict__ qb,
        const u16* __restrict__ kb, const u16* __restrict__ vT,
        const u16* __restrict__ tokens, float* __restrict__ cls_out,
        float* __restrict__ part2) {
    __shared__ u16 sh[9216];                  // Q-stage[128][72] -> Ks[64][72]|VTs[64][72]
    __shared__ float redp[8];

    const int bid = blockIdx.x;
    const int logical = (bid & 7) * 192 + (bid >> 3);   // 1536 = 8 XCD chunks x 192
    const int bh = logical >> 1;
    const int b = bh / NHH, h = bh % NHH;
    const int q0 = (logical & 1) * 128;
    const int tid = threadIdx.x;
    const int w = tid >> 6, l = tid & 63;
    const int g = l >> 4, lq = l & 15;

    {
        const u16* qbase = qb + (size_t)(b*197)*768 + h*64;
#pragma unroll
        for (int it = 0; it < 8; ++it) {
            int idx = tid + it*256;
            int r = idx >> 4, c = idx & 15;
            int gr = q0 + r; if (gr > 196) gr = 196;
            *(uint2*)&sh[r*72 + c*4] = *(const uint2*)(qbase + (size_t)gr*768 + c*4);
        }
    }
    __syncthreads();
    bf16x8 qfr[2][2];
#pragma unroll
    for (int s2 = 0; s2 < 2; ++s2)
#pragma unroll
        for (int s = 0; s < 2; ++s)
            qfr[s2][s] = *(const bf16x8*)&sh[(s2*64 + w*16 + lq)*72 + s*32 + g*8];

    u16* Ks  = sh;
    u16* VTs = sh + 4608;

    f32x4 acco[2][4];
#pragma unroll
    for (int s2 = 0; s2 < 2; ++s2)
#pragma unroll
        for (int i = 0; i < 4; ++i) acco[s2][i] = (f32x4){0.f,0.f,0.f,0.f};
    float S[2] = {0.f, 0.f};

    const int srcA = lq + ((l & 16) ? 32 : 0);
    const u16* krow = kb + (size_t)(b*197)*768 + h*64;
    const u16* vbase = vT + (size_t)bh*64*SQP;

    uint2 kreg[4], vreg[4];
    auto issueKV = [&](int tt) {
        const int t0 = tt * 64;
#pragma unroll
        for (int it = 0; it < 4; ++it) {
            int idx = tid + it*256;
            int r = idx >> 4, c = idx & 15;
            int gt = t0 + r; if (gt > 196) gt = 196;
            kreg[it] = *(const uint2*)(krow + (size_t)gt*768 + c*4);
            vreg[it] = *(const uint2*)(vbase + (size_t)r*SQP + t0 + c*4);
        }
    };
    issueKV(0);

    for (int tt = 0; tt < 4; ++tt) {
        __syncthreads();
#pragma unroll
        for (int it = 0; it < 4; ++it) {
            int idx = tid + it*256;
            int r = idx >> 4, c = idx & 15;
            *(uint2*)&Ks[r*72 + c*4]  = kreg[it];
            *(uint2*)&VTs[r*72 + c*4] = vreg[it];
        }
        if (tt < 3) issueKV(tt + 1);
        __syncthreads();

        const int t0 = tt * 64;
#pragma unroll
        for (int s2 = 0; s2 < 2; ++s2) {
            f32x4 accp[4];
#pragma unroll
            for (int i = 0; i < 4; ++i) accp[i] = (f32x4){0.f,0.f,0.f,0.f};
            __builtin_amdgcn_s_setprio(1);
#pragma unroll
            for (int s = 0; s < 2; ++s) {
#pragma unroll
                for (int tb = 0; tb < 4; ++tb) {
                    bf16x8 kf = *(const bf16x8*)&Ks[(tb*16 + lq)*72 + s*32 + g*8];
                    accp[tb] = __builtin_amdgcn_mfma_f32_16x16x32_bf16(kf, qfr[s2][s], accp[tb], 0, 0, 0);
                }
            }
            __builtin_amdgcn_s_setprio(0);

            unsigned pk[4][2];
#pragma unroll
            for (int tb = 0; tb < 4; ++tb) {
                int tbase = t0 + tb*16 + g*4;
                float p0 = (tbase + 0 < 197) ? __expf(accp[tb][0] * 0.125f) : 0.f;
                float p1 = (tbase + 1 < 197) ? __expf(accp[tb][1] * 0.125f) : 0.f;
                float p2 = (tbase + 2 < 197) ? __expf(accp[tb][2] * 0.125f) : 0.f;
                float p3 = (tbase + 3 < 197) ? __expf(accp[tb][3] * 0.125f) : 0.f;
                S[s2] += (p0 + p1) + (p2 + p3);
                asm("v_cvt_pk_bf16_f32 %0, %1, %2" : "=v"(pk[tb][0]) : "v"(p0), "v"(p1));
                asm("v_cvt_pk_bf16_f32 %0, %1, %2" : "=v"(pk[tb][1]) : "v"(p2), "v"(p3));
            }

#pragma unroll
            for (int s = 0; s < 2; ++s) {
                union { unsigned u[4]; bf16x8 v; } bp;
#pragma unroll
                for (int c = 0; c < 4; ++c) {
                    int src = srcA + ((c >= 2) ? 16 : 0);
                    unsigned v0 = (unsigned)__shfl((int)pk[2*s + 0][c & 1], src);
                    unsigned v1 = (unsigned)__shfl((int)pk[2*s + 1][c & 1], src);
                    bp.u[c] = (l & 32) ? v1 : v0;
                }
                __builtin_amdgcn_s_setprio(1);
#pragma unroll
                for (int dblk = 0; dblk < 4; ++dblk) {
                    bf16x8 vf = *(const bf16x8*)&VTs[(dblk*16 + lq)*72 + s*32 + g*8];
                    acco[s2][dblk] = __builtin_amdgcn_mfma_f32_16x16x32_bf16(vf, bp.v, acco[s2][dblk], 0, 0, 0);
                }
                __builtin_amdgcn_s_setprio(0);
            }
        }
    }

    float invS[2];
#pragma unroll
    for (int s2 = 0; s2 < 2; ++s2) {
        S[s2] += __shfl_xor(S[s2], 16);
        S[s2] += __shfl_xor(S[s2], 32);
        invS[s2] = 1.f / S[s2];
    }

    // register epilogue: lane's acco covers fixed q row (q0+s2*64+w*16+lq),
    // d = dblk*16 + g*4 + r (4 consecutive per dblk). Stats + cls write direct.
    float ps = 0.f, ps2v = 0.f;
#pragma unroll
    for (int s2 = 0; s2 < 2; ++s2) {
        const int q_glob = q0 + s2*64 + w*16 + lq;
        if (q_glob < 197) {
            const u16* trow = tokens + (size_t)(b*197 + q_glob)*768 + h*64;
            float* crow = cls_out + (size_t)b*768 + h*64;
#pragma unroll
            for (int dblk = 0; dblk < 4; ++dblk) {
                int d0 = dblk*16 + g*4;
                union { u16 u[4]; uint2 v; } tb_;
                tb_.v = *(const uint2*)(trow + d0);
                float4 t;
                t.x = bf2f(tb_.u[0]) + acco[s2][dblk][0] * invS[s2];
                t.y = bf2f(tb_.u[1]) + acco[s2][dblk][1] * invS[s2];
                t.z = bf2f(tb_.u[2]) + acco[s2][dblk][2] * invS[s2];
                t.w = bf2f(tb_.u[3]) + acco[s2][dblk][3] * invS[s2];
                ps   += (t.x + t.y) + (t.z + t.w);
                ps2v += (t.x*t.x + t.y*t.y) + (t.z*t.z + t.w*t.w);
                if (q_glob == 0) *(float4*)(crow + d0) = t;
            }
        }
    }

#pragma unroll
    for (int off = 1; off < 64; off <<= 1) {
        ps   += __shfl_xor(ps,   off);
        ps2v += __shfl_xor(ps2v, off);
    }
    if (l == 0) { redp[w*2] = ps; redp[w*2 + 1] = ps2v; }
    __syncthreads();
    if (tid == 0) {
        float a = redp[0] + redp[2] + redp[4] + redp[6];
        float c = redp[1] + redp[3] + redp[5] + redp[7];
        part2[logical*2]     = a;             // slot = bh*2 + half
        part2[logical*2 + 1] = c;
    }
}

// ---------------- MLP(cls) k-split partials: grid (16 bgroups, 3 o-tiles, 8 k-slices) ----------------
__global__ __launch_bounds__(256) void mlp_part(const float* __restrict__ cls_out,
        const float* __restrict__ part2, const float* __restrict__ ln2_g,
        const float* __restrict__ ln2_b, const float* __restrict__ w_enc,
        float* __restrict__ mpart) {
    __shared__ float y0[4][96];
    __shared__ float mu4[4], rs4[4];
    const int bg = blockIdx.x;                // samples 4bg..4bg+3
    const int n  = blockIdx.y * 256 + threadIdx.x;
    const int ks = blockIdx.z;
    const int k0 = ks * 96;
    if (threadIdx.x < 4) {
        int b = bg*4 + threadIdx.x;
        float s1 = 0.f, s2 = 0.f;
        for (int i = 0; i < 24; ++i) {
            s1 += part2[(b*24 + i)*2];
            s2 += part2[(b*24 + i)*2 + 1];
        }
        float mu = s1 * (1.f / (float)LNN);
        float var = s2 * (1.f / (float)LNN) - mu*mu;
        mu4[threadIdx.x] = mu;
        rs4[threadIdx.x] = rsqrtf(var + 1e-5f);
    }
    __syncthreads();
    if (threadIdx.x < 96) {
        int k = k0 + threadIdx.x;
        float gk = ln2_g[k], bk_ = ln2_b[k];
#pragma unroll
        for (int i = 0; i < 4; ++i) {
            float c = cls_out[(size_t)(bg*4 + i)*768 + k];
            y0[i][threadIdx.x] = (c - mu4[i]) * rs4[i] * gk + bk_;
        }
    }
    __syncthreads();
    if (n < 768) {
        float a0 = 0.f, a1 = 0.f, a2 = 0.f, a3 = 0.f;
#pragma unroll 8
        for (int k = 0; k < 96; ++k) {
            float wv = w_enc[(size_t)(k0 + k)*768 + n];
            a0 += y0[0][k] * wv;
            a1 += y0[1][k] * wv;
            a2 += y0[2][k] * wv;
            a3 += y0[3][k] * wv;
        }
        mpart[((size_t)(bg*4 + 0)*8 + ks)*768 + n] = a0;
        mpart[((size_t)(bg*4 + 1)*8 + ks)*768 + n] = a1;
        mpart[((size_t)(bg*4 + 2)*8 + ks)*768 + n] = a2;
        mpart[((size_t)(bg*4 + 3)*8 + ks)*768 + n] = a3;
    }
}

// ---------------- head: fused mlp_fin + logits partials ----------------
__global__ __launch_bounds__(256) void logits_kernel(const float* __restrict__ mpart,
        const float* __restrict__ b_enc, const float* __restrict__ cls_out,
        const float* __restrict__ w_head, float* __restrict__ lpart) {
    __shared__ float xr[4][96];
    const int bg = blockIdx.x;                // 16 -> samples 4bg..4bg+3
    const int o  = blockIdx.y * 256 + threadIdx.x;
    const int ks = blockIdx.z;                // 8 -> k0 = 96*ks
    const int k0 = ks * 96;
    if (threadIdx.x < 96) {
        int k = k0 + threadIdx.x;
        float be = b_enc[k];
#pragma unroll
        for (int i = 0; i < 4; ++i) {
            int b = bg*4 + i;
            float a = be;
#pragma unroll
            for (int ks2 = 0; ks2 < 8; ++ks2)
                a += mpart[((size_t)b*8 + ks2)*768 + k];
            xr[i][threadIdx.x] = cls_out[(size_t)b*768 + k] + fmaxf(a, 0.f);
        }
    }
    __syncthreads();
    if (o < NOUT) {
        float a0 = 0.f, a1 = 0.f, a2 = 0.f, a3 = 0.f;
#pragma unroll 8
        for (int k = 0; k < 96; ++k) {
            float wv = w_head[(size_t)(k0 + k)*NOUT + o];
            a0 += xr[0][k] * wv;
            a1 += xr[1][k] * wv;
            a2 += xr[2][k] * wv;
            a3 += xr[3][k] * wv;
        }
        lpart[((size_t)(bg*4 + 0)*8 + ks)*NOUT + o] = a0;
        lpart[((size_t)(bg*4 + 1)*8 + ks)*NOUT + o] = a1;
        lpart[((size_t)(bg*4 + 2)*8 + ks)*NOUT + o] = a2;
        lpart[((size_t)(bg*4 + 3)*8 + ks)*NOUT + o] = a3;
    }
}

__global__ __launch_bounds__(256) void softmax_kernel(const float* __restrict__ lpart,
        const float* __restrict__ b_head, float* __restrict__ outp) {
    __shared__ float red[8];
    const int b = blockIdx.x, tid = threadIdx.x;
    const int w = tid >> 6, l = tid & 63;
    float v[4];
    float mx = -1e30f;
#pragma unroll
    for (int i = 0; i < 4; ++i) {
        int t = tid + i*256;
        if (t < NOUT) {
            float a = b_head[t];
#pragma unroll
            for (int ks = 0; ks < 8; ++ks)
                a += lpart[((size_t)b*8 + ks)*NOUT + t];
            v[i] = a;
        } else v[i] = -1e30f;
        mx = fmaxf(mx, v[i]);
    }
    for (int off = 32; off; off >>= 1) mx = fmaxf(mx, __shfl_xor(mx, off));
    if (l == 0) red[w] = mx;
    __syncthreads();
    if (tid == 0) red[4] = fmaxf(fmaxf(red[0], red[1]), fmaxf(red[2], red[3]));
    __syncthreads();
    const float m = red[4];
    float s = 0.f;
#pragma unroll
    for (int i = 0; i < 4; ++i) { v[i] = __expf(v[i] - m); s += v[i]; }
    for (int off = 32; off; off >>= 1) s += __shfl_xor(s, off);
    if (l == 0) red[w] = s;
    __syncthreads();
    if (tid == 0) red[5] = red[0] + red[1] + red[2] + red[3];
    __syncthreads();
    const float inv = 1.f / red[5];
#pragma unroll
    for (int i = 0; i < 4; ++i) {
        int t = tid + i*256;
        if (t < NOUT) outp[(size_t)b*NOUT + t] = v[i] * inv;
    }
}

// ---------------- launch ----------------
extern "C" void kernel_launch(void* const* d_in, const int* in_sizes, int n_in,
                              void* d_out, int out_size, void* d_ws, size_t ws_size,
                              hipStream_t stream) {
    (void)in_sizes; (void)n_in; (void)out_size; (void)ws_size;
    const float* images = (const float*)d_in[0];
    const float* w_map  = (const float*)d_in[1];
    const float* b_map  = (const float*)d_in[2];
    const float* cls_tok= (const float*)d_in[3];
    const float* ln1_g  = (const float*)d_in[4];
    const float* ln1_b  = (const float*)d_in[5];
    const float* wq     = (const float*)d_in[6];
    const float* bq     = (const float*)d_in[7];
    const float* wk     = (const float*)d_in[8];
    const float* bk     = (const float*)d_in[9];
    const float* wv     = (const float*)d_in[10];
    const float* bv     = (const float*)d_in[11];
    const float* ln2_g  = (const float*)d_in[12];
    const float* ln2_b  = (const float*)d_in[13];
    const float* w_enc  = (const float*)d_in[14];
    const float* b_enc  = (const float*)d_in[15];
    const float* w_head = (const float*)d_in[16];
    const float* b_head = (const float*)d_in[17];
    float* out = (float*)d_out;
    float* ws = (float*)d_ws;

    float* pos    = ws;                     // 151296
    float* tokens = pos + 151296;           // tokens_bf overlay (u16, 19.4 MB used of slot)
    float* x      = tokens + 9682944;       // spare (layout stability)
    float* q      = x + 9682944;            // imb overlay, then qb
    float* kk     = q + 9682944;            // wt(w_map) overlay, then kb
    float* vv     = kk + 9682944;           // vT bf16 [768][64][256]
    float* part   = vv + 9682944;           // 512 (spare)
    float* part2  = part + 512;             // 3072 (ln2 per-(b,h,qhalf) partials)
    float* mlp_o  = part2 + 3072;           // 49152 (spare)
    float* lpart  = mlp_o + 49152;          // 512000 (logit k-split partials)
    float* wqkvT  = lpart + 512000;         // 73728 f32-slots = 147456 u16 bf16
    float* gpart  = wqkvT + 73728;          // 4704 (gemm0 LN1 partials, 1176 groups)
    float* cpart  = gpart + 4704;           // 384 (cls LN1 partials)
    float* cls_o  = cpart + 384;            // 49152 (post-attn cls rows, f32)
    float* mpart  = cls_o + 49152;          // 393216 (mlp k-split partials)

    u16* tkb = (u16*)tokens;   // bf16 tokens (residual), L2-resident
    u16* imb = (u16*)q;
    u16* wt  = (u16*)kk;
    u16* qbp = (u16*)q;
    u16* kbp = (u16*)kk;
    u16* vTp = (u16*)vv;
    u16* wTg = (u16*)wqkvT;

    prep_kernel<<<6100, 256, 0, stream>>>(cls_tok, images, w_map, wq, wk, wv,
                                          pos, tkb, cpart, imb, wt, wTg);
    gemm_mfma0<<<1176, 256, 0, stream>>>(imb, wt, b_map, pos, tkb, gpart);
    qkv_mfma<<<dim3(197, NHH), 256, 0, stream>>>(tkb, gpart, cpart, ln1_g, ln1_b, wTg,
                                                 bq, bk, bv, qbp, kbp, vTp);
    attn_mfma<<<BB_*NHH*2, 256, 0, stream>>>(qbp, kbp, vTp, tkb, cls_o, part2);
    mlp_part<<<dim3(16, 3, 8), 256, 0, stream>>>(cls_o, part2, ln2_g, ln2_b, w_enc, mpart);
    logits_kernel<<<dim3(16, 4, 8), 256, 0, stream>>>(mpart, b_enc, cls_o, w_head, lpart);
    softmax_kernel<<<BB_, 256, 0, stream>>>(lpart, b_head, out);
}